// Round 15
// baseline (169.147 us; speedup 1.0000x reference)
//
#include <hip/hip_runtime.h>

typedef unsigned short u16;
typedef unsigned int u32;
typedef unsigned long long u64;
typedef __attribute__((ext_vector_type(8))) short short8;
typedef __attribute__((ext_vector_type(4))) float f32x4;

typedef __attribute__((address_space(3))) void* lds_vp;
typedef const __attribute__((address_space(1))) void* gbl_vp;

#define GLOAD_LDS16(gsrc, ldst) \
  __builtin_amdgcn_global_load_lds((gbl_vp)(gsrc), (lds_vp)(ldst), 16, 0, 0)

#define MFMA_BF16(A, B, C) __builtin_amdgcn_mfma_f32_16x16x32_bf16((A), (B), (C), 0, 0, 0)
// NOTE (R9/R10 lesson): 16x16x16 bf16 MFMA compiles for gfx950 but produces
// NaN/garbage on silicon (not in the verified gfx950 intrinsic list). Do not use.

__device__ __forceinline__ u16 f2b(float f) {
  u32 u = __builtin_bit_cast(u32, f);
  u += 0x7fffu + ((u >> 16) & 1u);
  return (u16)(u >> 16);
}
__device__ __forceinline__ float b2f(u16 v) {
  return __builtin_bit_cast(float, ((u32)v) << 16);
}
__device__ __forceinline__ u32 cvtpk(float a, float b) {   // lo=bf16(a), hi=bf16(b)
  u32 r;
  asm("v_cvt_pk_bf16_f32 %0, %1, %2" : "=v"(r) : "v"(a), "v"(b));
  return r;
}
__device__ __forceinline__ u64 pack4(f32x4 v) {
  u32 lo = (u32)f2b(v[0]) | ((u32)f2b(v[1]) << 16);
  u32 hi = (u32)f2b(v[2]) | ((u32)f2b(v[3]) << 16);
  return (u64)lo | ((u64)hi << 32);
}

// ---------- fused fp32 -> bf16 conversion + RoPE table (one launch) --------
// Outputs contiguous in ws: xb (2097152 u4) | wqkv (786432 u4) | wo (262144 u4).
// Tail range (65536 threads) builds the cos/sin table.
__global__ void cvt_all(const float* __restrict__ x,  const float* __restrict__ wq,
                        const float* __restrict__ wk, const float* __restrict__ wv,
                        const float* __restrict__ wo, u16* __restrict__ out,
                        float2* __restrict__ tab) {
  int i = blockIdx.x * 256 + threadIdx.x;      // 12544*256 = 3211264 exactly
  if (i < 3145728) {
    const float4* src; int off;
    if (i < 2097152)      { src = (const float4*)x;  off = 0; }
    else if (i < 2359296) { src = (const float4*)wq; off = 2097152; }
    else if (i < 2621440) { src = (const float4*)wk; off = 2359296; }
    else if (i < 2883584) { src = (const float4*)wv; off = 2621440; }
    else                  { src = (const float4*)wo; off = 2883584; }
    float4 v = src[i - off];
    ushort4 o;
    o.x = f2b(v.x); o.y = f2b(v.y); o.z = f2b(v.z); o.w = f2b(v.w);
    ((ushort4*)out)[i] = o;
  } else {
    int t2 = i - 3145728;                      // 65536 = 2048 pos x 32 pairs
    int p = t2 >> 5, dp = t2 & 31;
    float inv = (float)pow(10000.0, -(double)dp / 32.0);
    float ang = (float)p * inv;
    tab[t2] = make_float2(cosf(ang), sinf(ang));
  }
}

// Q gets 0.125 * log2(e) so attention scores land in log2 domain.
#define QSCALE (0.125f * 1.4426950408889634f)

// ---------------- GEMM: deep-pipelined C = A @ Bt^T (R14-verbatim) ---------
template<int EPI, int BM>
__global__ __launch_bounds__(512, 2) void gemm_bt(
    const u16* __restrict__ A, const u16* __restrict__ Bt,
    float* __restrict__ Cf, int M, int N, int K,
    u16* __restrict__ qp, u16* __restrict__ kp, u16* __restrict__ vp,
    const float2* __restrict__ tab, const int* __restrict__ pos)
{
  constexpr int MR = BM / 64;                 // m-frags per wave; A stage groups
  __shared__ u16 As[2][BM * 64];              // [row][k], swizzled
  __shared__ u16 Bs[2][128 * 64];             // [col-row][k], swizzled
  const int t = threadIdx.x;
  const int l = t & 63, w = t >> 6;           // 8 waves
  const int wr = w >> 1, wc = w & 1;          // 4M x 2N
  const int tm = blockIdx.x * BM, tn = blockIdx.y * 128;
  const int cl = l & 15, ko = l >> 4;
  const int sw = l & 7;                       // read swizzle: row&7 == cl&7 == l&7
  const int srow = l >> 3, scb = l & 7;       // stage: 8 rows x 8 blocks per wave
  const int swsrc = (scb ^ srow) * 8;         // inverse-swizzled source col (u16)
  const int NT = K >> 6;                      // K-tiles (16 for K=1024, even)

  const u16* aSrc[MR];
  const u16* bSrc[2];
  #pragma unroll
  for (int g = 0; g < MR; ++g)
    aSrc[g] = A + (size_t)(tm + g * 64 + w * 8 + srow) * K + swsrc;
  #pragma unroll
  for (int g = 0; g < 2; ++g)
    bSrc[g] = Bt + (size_t)(tn + g * 64 + w * 8 + srow) * K + swsrc;

  f32x4 acc[MR][4] = {};

  auto stage = [&](int b, int kt_) {          // MR+2 gloads; wave covers 8 rows each
    const int kv = kt_ * 64;
    #pragma unroll
    for (int g = 0; g < MR; ++g)
      GLOAD_LDS16(aSrc[g] + kv, &As[b][(g * 64 + w * 8) * 64]);
    #pragma unroll
    for (int g = 0; g < 2; ++g)
      GLOAD_LDS16(bSrc[g] + kv, &Bs[b][(g * 64 + w * 8) * 64]);
  };

  auto tile = [&](int t_, int b) {            // b literal at both call sites
    if (t_ + 1 < NT) {                        // tile t_ landed; t_+1 in flight
      if constexpr (MR == 4) asm volatile("s_waitcnt vmcnt(6)" ::: "memory");
      else                   asm volatile("s_waitcnt vmcnt(4)" ::: "memory");
    } else {
      asm volatile("s_waitcnt vmcnt(0)" ::: "memory");
    }
    __builtin_amdgcn_s_barrier();
    short8 bfr[4][2];
    #pragma unroll
    for (int n = 0; n < 4; ++n) {
      int row = wc * 64 + n * 16 + cl;
      bfr[n][0] = *(const short8*)&Bs[b][row * 64 + ((ko ^ sw) << 3)];
      bfr[n][1] = *(const short8*)&Bs[b][row * 64 + (((4 + ko) ^ sw) << 3)];
    }
    #pragma unroll
    for (int m = 0; m < MR; ++m) {
      int row = wr * (MR * 16) + m * 16 + cl;
      short8 a0 = *(const short8*)&As[b][row * 64 + ((ko ^ sw) << 3)];
      short8 a1 = *(const short8*)&As[b][row * 64 + (((4 + ko) ^ sw) << 3)];
      __builtin_amdgcn_s_setprio(1);
      #pragma unroll
      for (int n = 0; n < 4; ++n) {
        acc[m][n] = MFMA_BF16(a0, bfr[n][0], acc[m][n]);
        acc[m][n] = MFMA_BF16(a1, bfr[n][1], acc[m][n]);
      }
      __builtin_amdgcn_s_setprio(0);
    }
    asm volatile("s_waitcnt lgkmcnt(0)" ::: "memory");   // all buf-b reads complete
    __builtin_amdgcn_sched_barrier(0);
    __builtin_amdgcn_s_barrier();             // every wave done READING buf b
    if (t_ + 2 < NT) stage(b, t_ + 2);        // safe to clobber b now
  };

  stage(0, 0);
  stage(1, 1);
  for (int kt = 0; kt < NT; kt += 2) {
    tile(kt, 0);
    tile(kt + 1, 1);
  }

  const int rl = (l >> 4) * 4;
  if constexpr (EPI == 2) {
    #pragma unroll
    for (int m = 0; m < MR; ++m)
      #pragma unroll
      for (int n = 0; n < 4; ++n) {
        int col = tn + wc * 64 + n * 16 + cl;
        #pragma unroll
        for (int r = 0; r < 4; ++r) {
          int row = tm + wr * (MR * 16) + m * 16 + rl + r;
          Cf[(size_t)row * N + col] = acc[m][n][r];
        }
      }
  } else {
    const int which = tn >> 10;               // uniform per block (tn mult of 128)
    if (which < 2) {
      // ---- fused RoPE on Q/K; Q also gets QSCALE ----
      u16* dst = which == 0 ? qp : kp;
      const float qs = which == 0 ? QSCALE : 1.0f;
      const int odd = cl & 1;
      #pragma unroll
      for (int m = 0; m < MR; ++m) {
        int row0 = tm + wr * (MR * 16) + m * 16 + rl;
        int b = row0 >> 11, s0 = row0 & 2047;
        int4 p4 = *(const int4*)&pos[s0];     // 4 consecutive positions (4-aligned)
        #pragma unroll
        for (int n = 0; n < 4; ++n) {
          int j0 = tn + wc * 64 + n * 16;
          int h = (j0 & 1023) >> 6;
          int d = (j0 & 63) + cl;
          int dp = d >> 1;
          #pragma unroll
          for (int r = 0; r < 4; ++r) {
            int p = ((const int*)&p4)[r];
            float2 cs = tab[(p << 5) + dp];
            float own = acc[m][n][r];
            float prt = __shfl_xor(own, 1);   // partner element d^1 (lane cl^1)
            float ssn = odd ? cs.y : -cs.y;   // even: x1*c - x2*s; odd: x2*c + x1*s
            float out = (own * cs.x + prt * ssn) * qs;
            dst[(size_t)((b * 16 + h) * 2048 + (s0 + r)) * 64 + d] = f2b(out);
          }
        }
      }
    } else {
      // ---- V: scatter transposed [B][H][64][S] ----
      #pragma unroll
      for (int m = 0; m < MR; ++m)
        #pragma unroll
        for (int n = 0; n < 4; ++n) {
          int j0 = tn + wc * 64 + n * 16;
          int h = (j0 & 1023) >> 6;
          int d = (j0 & 63) + cl;
          #pragma unroll
          for (int r = 0; r < 4; ++r) {
            int i = tm + wr * (MR * 16) + m * 16 + rl + r;
            int b = i >> 11, s = i & 2047;
            vp[(size_t)((b * 16 + h) * 64 + d) * 2048 + s] = f2b(acc[m][n][r]);
          }
        }
    }
  }
}

// ---------------- causal flash attention, v11: KVBLK=128 -------------------
// v10 per-64-key compute body verbatim, but each barrier pair now covers a
// 128-key tile processed as two sequential halves: {stage(4 gloads) |
// vmcnt(4) | barrier | half0{QK,softmax,Ps,drain,PV} | half1{...} | barrier}.
// Halves the barrier/stage/vmcnt count (34 -> ~18 steps/block). Fixed-max
// softmax now exp2(s) directly (common scale cancels in o/l). LDS 80KB
// (Ks 2x16 + Vs 2x16 + Ps 16) -> 2 blocks/CU = 160KB exactly.
__global__ __launch_bounds__(512, 3) void attn_fwd(
    const u16* __restrict__ Q, const u16* __restrict__ Kg,
    const u16* __restrict__ Vt, u16* __restrict__ Ob)
{
  __shared__ u16 Ks[2][128 * 64];   // [key][d], swizzled (row = 64 u16)
  __shared__ u16 Vs[2][64 * 128];   // [d][key], swizzled (row = 128 u16)
  __shared__ u16 Ps[8][16 * 64];    // per-wave P [q][64-key half], swizzled
  const int t = threadIdx.x;
  const int l = t & 63, w = t >> 6;           // w in [0,8)
  const int bh = blockIdx.y, b = bh >> 4, h = bh & 15;
  const int bx = blockIdx.x;                  // [0,8)
  const int cl = l & 15, ko = l >> 4;
  const int srow = l >> 3, scb = l & 7;       // K stage: 8 rows x 8 colblks
  const int vrow = l >> 4, vcb = l & 15;      // V stage: 4 rows x 16 colblks
  const u16* Kb = Kg + (size_t)bh * 2048 * 64;
  const u16* Vb = Vt + (size_t)bh * 64 * 2048;

  #pragma unroll 1
  for (int seg = 0; seg < 2; ++seg) {
    const int qtile = seg == 0 ? (7 - bx) : (8 + bx);
    const int qb = qtile * 128;
    const int qw = qb + w * 16;               // 16 q-rows per wave
    const int ntp = (qtile + 2) & ~1;         // 128-key tiles, padded even (<=16)

    short8 qf[2];                   // B-frag: lane&15 = q, elems = d
    {
      const u16* qr = Q + (size_t)(bh * 2048 + qw + cl) * 64 + ko * 8;
      qf[0] = *(const short8*)qr;
      qf[1] = *(const short8*)(qr + 32);
    }
    f32x4 o[4] = {};                // O^T: col=q=lane&15, reg r -> d = db*16+ko*4+r
    float lpart = 0.f;              // per-lane partial sum (reduced at epilogue)

    auto stage = [&](int bf, int kt_) {       // 4 gloads/wave per 128-key tile
      const int kv_ = kt_ * 128;
      #pragma unroll
      for (int g = 0; g < 2; ++g) {           // K: 16 rows/wave, 8 rows/gload
        int r0 = w * 16 + g * 8;
        int row = r0 + srow;
        int gc = (scb ^ (row & 7)) * 8;       // inverse-swizzled source col (u16)
        GLOAD_LDS16(Kb + (size_t)(kv_ + row) * 64 + gc, &Ks[bf][r0 * 64]);
      }
      #pragma unroll
      for (int g = 0; g < 2; ++g) {           // V: 8 d-rows/wave, 4 rows/gload
        int r0 = w * 8 + g * 4;
        int row = r0 + vrow;
        int gc = (vcb ^ (row & 7)) * 8;       // 16 colblks/row, XOR low 3 bits
        GLOAD_LDS16(Vb + (size_t)row * 2048 + kv_ + gc, &Vs[bf][r0 * 128]);
      }
    };

    auto step = [&](int kt, int bf) {         // bf is a literal at both call sites
      const int kv = kt * 128;
      if (kt + 1 < ntp) {
        stage(bf ^ 1, kt + 1);
        asm volatile("s_waitcnt vmcnt(4)" ::: "memory");  // tile kt landed
      } else {
        asm volatile("s_waitcnt vmcnt(0)" ::: "memory");
      }
      __builtin_amdgcn_s_barrier();
      #pragma unroll
      for (int hf = 0; hf < 2; ++hf) {
        const int kvh = kv + hf * 64;
        if (kvh <= qw + 15) {            // wave-uniform causal gate (=> kvh <= qw)
          // ---- QK^T (swapped): s[kk] = K-half x Q -> S^T ----
          f32x4 s[4] = {};
          __builtin_amdgcn_s_setprio(1);
          #pragma unroll
          for (int kk = 0; kk < 4; ++kk) {
            int row = (hf * 4 + kk) * 16 + cl, sws = row & 7;   // row = key
            short8 k0 = *(const short8*)&Ks[bf][row * 64 + ((ko ^ sws) << 3)];
            short8 k1 = *(const short8*)&Ks[bf][row * 64 + (((4 + ko) ^ sws) << 3)];
            s[kk] = MFMA_BF16(k0, qf[0], s[kk]);
            s[kk] = MFMA_BF16(k1, qf[1], s[kk]);
          }
          __builtin_amdgcn_s_setprio(0);
          // V-frags for this half: 8 ds_reads overlap the softmax VALU
          short8 vf[4][2];
          #pragma unroll
          for (int db = 0; db < 4; ++db) {
            int row = db * 16 + cl, sws = row & 7;      // row = d
            int cb0 = hf * 8 + ko, cb1 = hf * 8 + 4 + ko;
            vf[db][0] = *(const short8*)&Vs[bf][row * 128 + ((cb0 ^ sws) << 3)];
            vf[db][1] = *(const short8*)&Vs[bf][row * 128 + ((cb1 ^ sws) << 3)];
          }
          // s[kk][r]: q = qw+cl, key = kvh + kk*16 + ko*4 + r (in-lane per q)
          if (kvh + 63 > qw) {             // half touches the diagonal
            int q = qw + cl;
            #pragma unroll
            for (int kk = 0; kk < 4; ++kk) {
              int key0 = kvh + kk * 16 + ko * 4;
              #pragma unroll
              for (int r = 0; r < 4; ++r)
                if (key0 + r > q) s[kk][r] = -1e30f;
            }
          }
          // ---- fixed-max softmax: p = exp2(s) directly (scale cancels) ----
          f32x4 p[4];
          #pragma unroll
          for (int kk = 0; kk < 4; ++kk)
            #pragma unroll
            for (int j = 0; j < 4; ++j)
              p[kk][j] = exp2f(s[kk][j]);
          f32x4 vs_;
          #pragma unroll
          for (int j = 0; j < 4; ++j)
            vs_[j] = (p[0][j] + p[1][j]) + (p[2][j] + p[3][j]);
          lpart += (vs_[0] + vs_[1]) + (vs_[2] + vs_[3]);
          // write P[q][key-in-half] (swizzled), cvt_pk pairs -> b64 stores
          {
            int prow = cl, sws = cl & 7;
            #pragma unroll
            for (int kk = 0; kk < 4; ++kk) {
              int key0 = kk * 16 + ko * 4;
              int cb = key0 >> 3, ci = key0 & 7;
              u32 c0 = cvtpk(p[kk][0], p[kk][1]);
              u32 c1 = cvtpk(p[kk][2], p[kk][3]);
              *(u64*)&Ps[w][prow * 64 + ((cb ^ sws) << 3) + ci] = (u64)c0 | ((u64)c1 << 32);
            }
          }
          // cross-lane LDS RAW fence + rule-18 sched fence
          asm volatile("s_waitcnt lgkmcnt(0)" ::: "memory");
          __builtin_amdgcn_sched_barrier(0);
          // ---- PV (swapped): o[db] += V^T-half x P -> O^T ----
          short8 pa[2];
          {
            int row = cl, sws = cl & 7;
            pa[0] = *(const short8*)&Ps[w][row * 64 + ((ko ^ sws) << 3)];
            pa[1] = *(const short8*)&Ps[w][row * 64 + (((4 + ko) ^ sws) << 3)];
          }
          __builtin_amdgcn_s_setprio(1);
          #pragma unroll
          for (int db = 0; db < 4; ++db) {
            o[db] = MFMA_BF16(vf[db][0], pa[0], o[db]);
            o[db] = MFMA_BF16(vf[db][1], pa[1], o[db]);
          }
          __builtin_amdgcn_s_setprio(0);
        }
      }
      asm volatile("" ::: "memory");     // keep LDS reads on this side of the barrier
      __builtin_amdgcn_s_barrier();      // reads done before next stage overwrites
    };

    stage(0, 0);
    for (int kt = 0; kt < ntp; kt += 2) {   // ntp even; bf literal per call site
      step(kt, 0);
      step(kt + 1, 1);
    }
    // ---- epilogue: lane owns q = qw+cl; d = db*16+ko*4+r ----
    {
      float ts = lpart;
      ts += __shfl_xor(ts, 16);
      ts += __shfl_xor(ts, 32);
      float inv = 1.0f / ts;
      u16* ob = Ob + (size_t)(b * 2048 + qw + cl) * 1024 + h * 64 + ko * 4;
      #pragma unroll
      for (int db = 0; db < 4; ++db) {
        f32x4 ov;
        #pragma unroll
        for (int j = 0; j < 4; ++j) ov[j] = o[db][j] * inv;
        *(u64*)&ob[db * 16] = pack4(ov);
      }
    }
    // trailing s_barrier of the last step covers LDS reuse across segments
  }
}

extern "C" void kernel_launch(void* const* d_in, const int* in_sizes, int n_in,
                              void* d_out, int out_size, void* d_ws, size_t ws_size,
                              hipStream_t stream) {
  const float* x  = (const float*)d_in[0];
  const float* Wq = (const float*)d_in[1];
  const float* Wk = (const float*)d_in[2];
  const float* Wv = (const float*)d_in[3];
  const float* Wo = (const float*)d_in[4];
  const int* tok  = (const int*)d_in[5];

  char* ws = (char*)d_ws;
  u16*   xb   = (u16*)(ws);                        // 16 MiB (x bf16; reused as attn-out)
  u16*   wqkv = (u16*)(ws + (16u << 20));          //  6 MiB
  u16*   wo   = (u16*)(ws + (22u << 20));          //  2 MiB
  u16*   qws  = (u16*)(ws + (24u << 20));          // 16 MiB [B][H][S][64]
  u16*   kws  = (u16*)(ws + (40u << 20));          // 16 MiB [B][H][S][64]
  u16*   vws  = (u16*)(ws + (56u << 20));          // 16 MiB [B][H][64][S]
  float2* tab = (float2*)(ws + (72u << 20));       // 512 KiB

  cvt_all<<<12544, 256, 0, stream>>>(x, Wq, Wk, Wv, Wo, xb, tab);

  gemm_bt<1, 128><<<dim3(64, 24), 512, 0, stream>>>(xb, wqkv, nullptr, 8192, 3072, 1024,
                                                    qws, kws, vws, tab, tok);
  attn_fwd<<<dim3(8, 64), 512, 0, stream>>>(qws, kws, vws, xb);
  gemm_bt<2, 128><<<dim3(64, 8), 512, 0, stream>>>(xb, wo, (float*)d_out, 8192, 1024, 1024,
                                                   nullptr, nullptr, nullptr, nullptr, nullptr);
}

// Round 16
// 166.989 us; speedup vs baseline: 1.0129x; 1.0129x over previous
//
#include <hip/hip_runtime.h>

typedef unsigned short u16;
typedef unsigned int u32;
typedef unsigned long long u64;
typedef __attribute__((ext_vector_type(8))) short short8;
typedef __attribute__((ext_vector_type(4))) float f32x4;

typedef __attribute__((address_space(3))) void* lds_vp;
typedef const __attribute__((address_space(1))) void* gbl_vp;

#define GLOAD_LDS16(gsrc, ldst) \
  __builtin_amdgcn_global_load_lds((gbl_vp)(gsrc), (lds_vp)(ldst), 16, 0, 0)

#define MFMA_BF16(A, B, C) __builtin_amdgcn_mfma_f32_16x16x32_bf16((A), (B), (C), 0, 0, 0)
// NOTE (R9/R10 lesson): 16x16x16 bf16 MFMA compiles for gfx950 but produces
// NaN/garbage on silicon (not in the verified gfx950 intrinsic list). Do not use.

__device__ __forceinline__ u16 f2b(float f) {
  u32 u = __builtin_bit_cast(u32, f);
  u += 0x7fffu + ((u >> 16) & 1u);
  return (u16)(u >> 16);
}
__device__ __forceinline__ float b2f(u16 v) {
  return __builtin_bit_cast(float, ((u32)v) << 16);
}
__device__ __forceinline__ u32 cvtpk(float a, float b) {   // lo=bf16(a), hi=bf16(b)
  u32 r;
  asm("v_cvt_pk_bf16_f32 %0, %1, %2" : "=v"(r) : "v"(a), "v"(b));
  return r;
}
__device__ __forceinline__ u64 pack4(f32x4 v) {
  u32 lo = (u32)f2b(v[0]) | ((u32)f2b(v[1]) << 16);
  u32 hi = (u32)f2b(v[2]) | ((u32)f2b(v[3]) << 16);
  return (u64)lo | ((u64)hi << 32);
}

// ---------- fused fp32 -> bf16 conversion + RoPE table (one launch) --------
// Outputs contiguous in ws: xb (2097152 u4) | wqkv (786432 u4) | wo (262144 u4).
// Tail range (65536 threads) builds the cos/sin table.
__global__ void cvt_all(const float* __restrict__ x,  const float* __restrict__ wq,
                        const float* __restrict__ wk, const float* __restrict__ wv,
                        const float* __restrict__ wo, u16* __restrict__ out,
                        float2* __restrict__ tab) {
  int i = blockIdx.x * 256 + threadIdx.x;      // 12544*256 = 3211264 exactly
  if (i < 3145728) {
    const float4* src; int off;
    if (i < 2097152)      { src = (const float4*)x;  off = 0; }
    else if (i < 2359296) { src = (const float4*)wq; off = 2097152; }
    else if (i < 2621440) { src = (const float4*)wk; off = 2359296; }
    else if (i < 2883584) { src = (const float4*)wv; off = 2621440; }
    else                  { src = (const float4*)wo; off = 2883584; }
    float4 v = src[i - off];
    ushort4 o;
    o.x = f2b(v.x); o.y = f2b(v.y); o.z = f2b(v.z); o.w = f2b(v.w);
    ((ushort4*)out)[i] = o;
  } else {
    int t2 = i - 3145728;                      // 65536 = 2048 pos x 32 pairs
    int p = t2 >> 5, dp = t2 & 31;
    float inv = (float)pow(10000.0, -(double)dp / 32.0);
    float ang = (float)p * inv;
    tab[t2] = make_float2(cosf(ang), sinf(ang));
  }
}

// Q gets 0.125 * log2(e) so attention scores land in log2 domain.
#define QSCALE (0.125f * 1.4426950408889634f)

// ---------------- GEMM: deep-pipelined C = A @ Bt^T (R14-verbatim) ---------
template<int EPI, int BM>
__global__ __launch_bounds__(512, 2) void gemm_bt(
    const u16* __restrict__ A, const u16* __restrict__ Bt,
    float* __restrict__ Cf, int M, int N, int K,
    u16* __restrict__ qp, u16* __restrict__ kp, u16* __restrict__ vp,
    const float2* __restrict__ tab, const int* __restrict__ pos)
{
  constexpr int MR = BM / 64;                 // m-frags per wave; A stage groups
  __shared__ u16 As[2][BM * 64];              // [row][k], swizzled
  __shared__ u16 Bs[2][128 * 64];             // [col-row][k], swizzled
  const int t = threadIdx.x;
  const int l = t & 63, w = t >> 6;           // 8 waves
  const int wr = w >> 1, wc = w & 1;          // 4M x 2N
  const int tm = blockIdx.x * BM, tn = blockIdx.y * 128;
  const int cl = l & 15, ko = l >> 4;
  const int sw = l & 7;                       // read swizzle: row&7 == cl&7 == l&7
  const int srow = l >> 3, scb = l & 7;       // stage: 8 rows x 8 blocks per wave
  const int swsrc = (scb ^ srow) * 8;         // inverse-swizzled source col (u16)
  const int NT = K >> 6;                      // K-tiles (16 for K=1024, even)

  const u16* aSrc[MR];
  const u16* bSrc[2];
  #pragma unroll
  for (int g = 0; g < MR; ++g)
    aSrc[g] = A + (size_t)(tm + g * 64 + w * 8 + srow) * K + swsrc;
  #pragma unroll
  for (int g = 0; g < 2; ++g)
    bSrc[g] = Bt + (size_t)(tn + g * 64 + w * 8 + srow) * K + swsrc;

  f32x4 acc[MR][4] = {};

  auto stage = [&](int b, int kt_) {          // MR+2 gloads; wave covers 8 rows each
    const int kv = kt_ * 64;
    #pragma unroll
    for (int g = 0; g < MR; ++g)
      GLOAD_LDS16(aSrc[g] + kv, &As[b][(g * 64 + w * 8) * 64]);
    #pragma unroll
    for (int g = 0; g < 2; ++g)
      GLOAD_LDS16(bSrc[g] + kv, &Bs[b][(g * 64 + w * 8) * 64]);
  };

  auto tile = [&](int t_, int b) {            // b literal at both call sites
    if (t_ + 1 < NT) {                        // tile t_ landed; t_+1 in flight
      if constexpr (MR == 4) asm volatile("s_waitcnt vmcnt(6)" ::: "memory");
      else                   asm volatile("s_waitcnt vmcnt(4)" ::: "memory");
    } else {
      asm volatile("s_waitcnt vmcnt(0)" ::: "memory");
    }
    __builtin_amdgcn_s_barrier();
    short8 bfr[4][2];
    #pragma unroll
    for (int n = 0; n < 4; ++n) {
      int row = wc * 64 + n * 16 + cl;
      bfr[n][0] = *(const short8*)&Bs[b][row * 64 + ((ko ^ sw) << 3)];
      bfr[n][1] = *(const short8*)&Bs[b][row * 64 + (((4 + ko) ^ sw) << 3)];
    }
    #pragma unroll
    for (int m = 0; m < MR; ++m) {
      int row = wr * (MR * 16) + m * 16 + cl;
      short8 a0 = *(const short8*)&As[b][row * 64 + ((ko ^ sw) << 3)];
      short8 a1 = *(const short8*)&As[b][row * 64 + (((4 + ko) ^ sw) << 3)];
      __builtin_amdgcn_s_setprio(1);
      #pragma unroll
      for (int n = 0; n < 4; ++n) {
        acc[m][n] = MFMA_BF16(a0, bfr[n][0], acc[m][n]);
        acc[m][n] = MFMA_BF16(a1, bfr[n][1], acc[m][n]);
      }
      __builtin_amdgcn_s_setprio(0);
    }
    asm volatile("s_waitcnt lgkmcnt(0)" ::: "memory");   // all buf-b reads complete
    __builtin_amdgcn_sched_barrier(0);
    __builtin_amdgcn_s_barrier();             // every wave done READING buf b
    if (t_ + 2 < NT) stage(b, t_ + 2);        // safe to clobber b now
  };

  stage(0, 0);
  stage(1, 1);
  for (int kt = 0; kt < NT; kt += 2) {
    tile(kt, 0);
    tile(kt + 1, 1);
  }

  const int rl = (l >> 4) * 4;
  if constexpr (EPI == 2) {
    #pragma unroll
    for (int m = 0; m < MR; ++m)
      #pragma unroll
      for (int n = 0; n < 4; ++n) {
        int col = tn + wc * 64 + n * 16 + cl;
        #pragma unroll
        for (int r = 0; r < 4; ++r) {
          int row = tm + wr * (MR * 16) + m * 16 + rl + r;
          Cf[(size_t)row * N + col] = acc[m][n][r];
        }
      }
  } else {
    const int which = tn >> 10;               // uniform per block (tn mult of 128)
    if (which < 2) {
      // ---- fused RoPE on Q/K; Q also gets QSCALE ----
      u16* dst = which == 0 ? qp : kp;
      const float qs = which == 0 ? QSCALE : 1.0f;
      const int odd = cl & 1;
      #pragma unroll
      for (int m = 0; m < MR; ++m) {
        int row0 = tm + wr * (MR * 16) + m * 16 + rl;
        int b = row0 >> 11, s0 = row0 & 2047;
        int4 p4 = *(const int4*)&pos[s0];     // 4 consecutive positions (4-aligned)
        #pragma unroll
        for (int n = 0; n < 4; ++n) {
          int j0 = tn + wc * 64 + n * 16;
          int h = (j0 & 1023) >> 6;
          int d = (j0 & 63) + cl;
          int dp = d >> 1;
          #pragma unroll
          for (int r = 0; r < 4; ++r) {
            int p = ((const int*)&p4)[r];
            float2 cs = tab[(p << 5) + dp];
            float own = acc[m][n][r];
            float prt = __shfl_xor(own, 1);   // partner element d^1 (lane cl^1)
            float ssn = odd ? cs.y : -cs.y;   // even: x1*c - x2*s; odd: x2*c + x1*s
            float out = (own * cs.x + prt * ssn) * qs;
            dst[(size_t)((b * 16 + h) * 2048 + (s0 + r)) * 64 + d] = f2b(out);
          }
        }
      }
    } else {
      // ---- V: scatter transposed [B][H][64][S] ----
      #pragma unroll
      for (int m = 0; m < MR; ++m)
        #pragma unroll
        for (int n = 0; n < 4; ++n) {
          int j0 = tn + wc * 64 + n * 16;
          int h = (j0 & 1023) >> 6;
          int d = (j0 & 63) + cl;
          #pragma unroll
          for (int r = 0; r < 4; ++r) {
            int i = tm + wr * (MR * 16) + m * 16 + rl + r;
            int b = i >> 11, s = i & 2047;
            vp[(size_t)((b * 16 + h) * 64 + d) * 2048 + s] = f2b(acc[m][n][r]);
          }
        }
    }
  }
}

// ---------------- causal flash attention, v12 = R14 body + exp2-direct -----
// 8 waves x 16 q-rows; block bx handles q-tiles (7-bx) and (8+bx) -> constant
// 34 steps/block; dbuf K/V counted vmcnt(2); T2 swizzle; fixed-max softmax
// with p = exp2(s) directly (common scale cancels in o/l); cvt_pk P-pack via
// Ps LDS; T5 setprio. (R15's KVBLK=128 variant reverted: neutral time, 3x
// bank conflicts from the 16-colblk V layout.)
__global__ __launch_bounds__(512, 3) void attn_fwd(
    const u16* __restrict__ Q, const u16* __restrict__ Kg,
    const u16* __restrict__ Vt, u16* __restrict__ Ob)
{
  __shared__ u16 Ks[2][64 * 64];    // [key][d], swizzled
  __shared__ u16 Vs[2][64 * 64];    // [d][key], swizzled
  __shared__ u16 Ps[8][16 * 64];    // per-wave P [q][key], swizzled
  const int t = threadIdx.x;
  const int l = t & 63, w = t >> 6;           // w in [0,8)
  const int bh = blockIdx.y, b = bh >> 4, h = bh & 15;
  const int bx = blockIdx.x;                  // [0,8)
  const int cl = l & 15, ko = l >> 4;
  const int srow = l >> 3;          // 0..7
  const int scb  = l & 7;
  const u16* Kb = Kg + (size_t)bh * 2048 * 64;
  const u16* Vb = Vt + (size_t)bh * 64 * 2048;

  #pragma unroll 1
  for (int seg = 0; seg < 2; ++seg) {
    const int qtile = seg == 0 ? (7 - bx) : (8 + bx);
    const int qb = qtile * 128;
    const int qw = qb + w * 16;               // 16 q-rows per wave
    const int nt = (qb >> 6) + 2;             // always even

    short8 qf[2];                   // B-frag: lane&15 = q, elems = d
    {
      const u16* qr = Q + (size_t)(bh * 2048 + qw + cl) * 64 + ko * 8;
      qf[0] = *(const short8*)qr;
      qf[1] = *(const short8*)(qr + 32);
    }
    f32x4 o[4] = {};                // O^T: col=q=lane&15, reg r -> d = db*16+ko*4+r
    float lpart = 0.f;              // per-lane partial sum (reduced at epilogue)

    auto stage = [&](int bf, int kt_) {
      const int kv_ = kt_ * 64;
      int r0 = w * 8;               // each wave stages 8 rows of K and of V
      int row = r0 + srow;
      int gc = (scb ^ (row & 7)) * 8;           // inverse-swizzled source col (u16)
      GLOAD_LDS16(Kb + (size_t)(kv_ + row) * 64 + gc, &Ks[bf][r0 * 64]);
      GLOAD_LDS16(Vb + (size_t)row * 2048 + kv_ + gc, &Vs[bf][r0 * 64]);
    };

    auto step = [&](int kt, int bf) {           // bf is a literal at both call sites
      const int kv = kt * 64;
      if (kt + 1 < nt) {
        stage(bf ^ 1, kt + 1);
        asm volatile("s_waitcnt vmcnt(2)" ::: "memory");  // tile kt landed
      } else {
        asm volatile("s_waitcnt vmcnt(0)" ::: "memory");
      }
      __builtin_amdgcn_s_barrier();
      if (kv <= qw + 15) {               // wave-uniform causal gate (=> kv <= qw)
        // ---- QK^T (swapped): s[kbk] = K-tile x Q -> S^T ----
        f32x4 s[4] = {};
        __builtin_amdgcn_s_setprio(1);
        #pragma unroll
        for (int kbk = 0; kbk < 4; ++kbk) {
          int row = kbk * 16 + cl, sws = row & 7;       // row = key (A-frag)
          short8 k0 = *(const short8*)&Ks[bf][row * 64 + ((ko ^ sws) << 3)];
          short8 k1 = *(const short8*)&Ks[bf][row * 64 + (((4 + ko) ^ sws) << 3)];
          s[kbk] = MFMA_BF16(k0, qf[0], s[kbk]);
          s[kbk] = MFMA_BF16(k1, qf[1], s[kbk]);
        }
        __builtin_amdgcn_s_setprio(0);
        // V-fragments hoisted: 8 independent ds_reads overlap the softmax VALU
        short8 vf[4][2];
        #pragma unroll
        for (int db = 0; db < 4; ++db) {
          int row = db * 16 + cl, sws = row & 7;        // row = d (A-frag)
          vf[db][0] = *(const short8*)&Vs[bf][row * 64 + ((ko ^ sws) << 3)];
          vf[db][1] = *(const short8*)&Vs[bf][row * 64 + (((4 + ko) ^ sws) << 3)];
        }
        // s[kbk][r]: q = qw+cl, key = kv+kbk*16+ko*4+r (in-lane per q)
        if (kv + 63 > qw) {              // tile touches the diagonal
          int q = qw + cl;
          #pragma unroll
          for (int kbk = 0; kbk < 4; ++kbk) {
            int key0 = kv + kbk * 16 + ko * 4;
            #pragma unroll
            for (int r = 0; r < 4; ++r)
              if (key0 + r > q) s[kbk][r] = -1e30f;
          }
        }
        // ---- fixed-max softmax: p = exp2(s) directly (scale cancels) ----
        f32x4 p[4];
        #pragma unroll
        for (int kbk = 0; kbk < 4; ++kbk)
          #pragma unroll
          for (int j = 0; j < 4; ++j)
            p[kbk][j] = exp2f(s[kbk][j]);
        f32x4 vs_;
        #pragma unroll
        for (int j = 0; j < 4; ++j)
          vs_[j] = (p[0][j] + p[1][j]) + (p[2][j] + p[3][j]);
        lpart += (vs_[0] + vs_[1]) + (vs_[2] + vs_[3]);
        // write P[q][key] (swizzled), cvt_pk pairs -> one b64 store per kbk
        {
          int prow = cl, sws = cl & 7;
          #pragma unroll
          for (int kbk = 0; kbk < 4; ++kbk) {
            int key0 = kbk * 16 + ko * 4;
            int cb = key0 >> 3, ci = key0 & 7;
            u32 c0 = cvtpk(p[kbk][0], p[kbk][1]);
            u32 c1 = cvtpk(p[kbk][2], p[kbk][3]);
            *(u64*)&Ps[w][prow * 64 + ((cb ^ sws) << 3) + ci] = (u64)c0 | ((u64)c1 << 32);
          }
        }
        // cross-lane LDS RAW fence (outside C memory model) + rule-18 sched fence
        asm volatile("s_waitcnt lgkmcnt(0)" ::: "memory");
        __builtin_amdgcn_sched_barrier(0);
        // ---- PV (swapped): o[db] += V^T-tile x P -> O^T ----
        short8 pa[2];
        {
          int row = cl, sws = cl & 7;
          pa[0] = *(const short8*)&Ps[w][row * 64 + ((ko ^ sws) << 3)];
          pa[1] = *(const short8*)&Ps[w][row * 64 + (((4 + ko) ^ sws) << 3)];
        }
        __builtin_amdgcn_s_setprio(1);
        #pragma unroll
        for (int db = 0; db < 4; ++db) {
          o[db] = MFMA_BF16(vf[db][0], pa[0], o[db]);
          o[db] = MFMA_BF16(vf[db][1], pa[1], o[db]);
        }
        __builtin_amdgcn_s_setprio(0);
      }
      asm volatile("" ::: "memory");     // keep LDS reads on this side of the barrier
      __builtin_amdgcn_s_barrier();      // reads done before next stage overwrites
    };

    stage(0, 0);
    for (int kt = 0; kt < nt; kt += 2) { // nt even; bf literal per call site
      step(kt, 0);
      step(kt + 1, 1);
    }
    // ---- epilogue: lane owns q = qw+cl; d = db*16+ko*4+r ----
    {
      float ts = lpart;
      ts += __shfl_xor(ts, 16);
      ts += __shfl_xor(ts, 32);
      float inv = 1.0f / ts;
      u16* ob = Ob + (size_t)(b * 2048 + qw + cl) * 1024 + h * 64 + ko * 4;
      #pragma unroll
      for (int db = 0; db < 4; ++db) {
        f32x4 ov;
        #pragma unroll
        for (int j = 0; j < 4; ++j) ov[j] = o[db][j] * inv;
        *(u64*)&ob[db * 16] = pack4(ov);
      }
    }
    // trailing s_barrier of the last step covers LDS reuse across segments
  }
}

extern "C" void kernel_launch(void* const* d_in, const int* in_sizes, int n_in,
                              void* d_out, int out_size, void* d_ws, size_t ws_size,
                              hipStream_t stream) {
  const float* x  = (const float*)d_in[0];
  const float* Wq = (const float*)d_in[1];
  const float* Wk = (const float*)d_in[2];
  const float* Wv = (const float*)d_in[3];
  const float* Wo = (const float*)d_in[4];
  const int* tok  = (const int*)d_in[5];

  char* ws = (char*)d_ws;
  u16*   xb   = (u16*)(ws);                        // 16 MiB (x bf16; reused as attn-out)
  u16*   wqkv = (u16*)(ws + (16u << 20));          //  6 MiB
  u16*   wo   = (u16*)(ws + (22u << 20));          //  2 MiB
  u16*   qws  = (u16*)(ws + (24u << 20));          // 16 MiB [B][H][S][64]
  u16*   kws  = (u16*)(ws + (40u << 20));          // 16 MiB [B][H][S][64]
  u16*   vws  = (u16*)(ws + (56u << 20));          // 16 MiB [B][H][64][S]
  float2* tab = (float2*)(ws + (72u << 20));       // 512 KiB

  cvt_all<<<12544, 256, 0, stream>>>(x, Wq, Wk, Wv, Wo, xb, tab);

  gemm_bt<1, 128><<<dim3(64, 24), 512, 0, stream>>>(xb, wqkv, nullptr, 8192, 3072, 1024,
                                                    qws, kws, vws, tab, tok);
  attn_fwd<<<dim3(8, 64), 512, 0, stream>>>(qws, kws, vws, xb);
  gemm_bt<2, 128><<<dim3(64, 8), 512, 0, stream>>>(xb, wo, (float*)d_out, 8192, 1024, 1024,
                                                   nullptr, nullptr, nullptr, nullptr, nullptr);
}